// Round 3
// baseline (498.988 us; speedup 1.0000x reference)
//
#include <hip/hip_runtime.h>

#define NN    4096
#define BB    4
#define INDIM 64
#define HD    256
#define KMAX  32
#define SLOTS 33   // K neighbors + self

// ---------------------------------------------------------------------------
// Kernel 1: XL = x@Wl + bl, XR = x@Wr + br   ([16384,64] @ [64,256])
// 256 threads/block, 32 nodes/block. x chunk transposed in LDS (pad 36).
// ---------------------------------------------------------------------------
__global__ __launch_bounds__(256) void xlr_kernel(
    const float* __restrict__ x,
    const float* __restrict__ Wl, const float* __restrict__ bl,
    const float* __restrict__ Wr, const float* __restrict__ br,
    float* __restrict__ XL, float* __restrict__ XR)
{
    __shared__ float xs[INDIM][36];   // [c][m], pad 36: 16B-aligned rows, spread write banks
    const int t = threadIdx.x;        // output column 0..255
    const int base = blockIdx.x * 32; // first node of this chunk

    // load 32x64 x-chunk as float4, store transposed
    #pragma unroll
    for (int r = 0; r < 2; ++r) {
        float4 xv4 = ((const float4*)x)[(size_t)base * (INDIM / 4) + r * 256 + t];
        int l = (r * 256 + t) * 4;
        int m = l >> 6, c = l & 63;
        xs[c + 0][m] = xv4.x;
        xs[c + 1][m] = xv4.y;
        xs[c + 2][m] = xv4.z;
        xs[c + 3][m] = xv4.w;
    }
    __syncthreads();

    float accl[32], accr[32];
    #pragma unroll
    for (int m = 0; m < 32; ++m) { accl[m] = 0.f; accr[m] = 0.f; }

    for (int c = 0; c < INDIM; ++c) {
        float wl = Wl[c * HD + t];
        float wr = Wr[c * HD + t];
        float xv[32];
        const float4* xp = (const float4*)&xs[c][0];   // broadcast reads
        float4* dst = (float4*)xv;
        #pragma unroll
        for (int q = 0; q < 8; ++q) dst[q] = xp[q];
        #pragma unroll
        for (int m = 0; m < 32; ++m) {
            accl[m] = fmaf(xv[m], wl, accl[m]);
            accr[m] = fmaf(xv[m], wr, accr[m]);
        }
    }

    float blv = bl[t], brv = br[t];
    #pragma unroll
    for (int m = 0; m < 32; ++m) {
        XL[(size_t)(base + m) * HD + t] = accl[m] + blv;
        XR[(size_t)(base + m) * HD + t] = accr[m] + brv;
    }
}

// ---------------------------------------------------------------------------
// Kernel 2: per-node fused GATv2 attention + aggregate + bias + LayerNorm.
// One block (256 thr) per node. Wave h == head h (D=64 == wavefront).
// ---------------------------------------------------------------------------
__global__ __launch_bounds__(256, 3) void gat_kernel(
    const float* __restrict__ adj,
    const float* __restrict__ XL, const float* __restrict__ XR,
    const float* __restrict__ att, const float* __restrict__ bias,
    const float* __restrict__ gamma, const float* __restrict__ beta,
    float* __restrict__ out)
{
    const int node = blockIdx.x;          // b*N + i
    const int b    = node >> 12;          // N = 4096
    const int i    = node & (NN - 1);
    const int t    = threadIdx.x;         // feature index h*64+d
    const int h    = t >> 6;              // head == wave
    const int lane = t & 63;

    __shared__ int   s_nbr[SLOTS];
    __shared__ float s_a[4][SLOTS];       // e, then alpha (per-head)
    __shared__ float s_red[4];
    __shared__ int   s_cnt;

    // hoisted independent loads — in flight under the adjacency scan
    const float xr    = XR[(size_t)node * HD + t];
    const float attv  = att[t];           // att is [H,D] flat = 256
    const float biasv = bias[t];
    const float gv    = gamma[t];
    const float bv    = beta[t];

    // ---- Phase A: scan adjacency row (16 KB), compact nonzero columns ----
    const float4* row = (const float4*)(adj + (size_t)node * NN);
    float4 v[4];
    #pragma unroll
    for (int r = 0; r < 4; ++r) v[r] = row[r * 256 + t];

    if (t == 0) s_cnt = 0;
    __syncthreads();

    #pragma unroll
    for (int r = 0; r < 4; ++r) {
        int j0 = (r * 256 + t) * 4;
        if (v[r].x > 0.f) { int p = atomicAdd(&s_cnt, 1); if (p < KMAX) s_nbr[p] = j0;     }
        if (v[r].y > 0.f) { int p = atomicAdd(&s_cnt, 1); if (p < KMAX) s_nbr[p] = j0 + 1; }
        if (v[r].z > 0.f) { int p = atomicAdd(&s_cnt, 1); if (p < KMAX) s_nbr[p] = j0 + 2; }
        if (v[r].w > 0.f) { int p = atomicAdd(&s_cnt, 1); if (p < KMAX) s_nbr[p] = j0 + 3; }
    }
    __syncthreads();
    int cnt = s_cnt; if (cnt > KMAX) cnt = KMAX;
    // fill slot cnt (self-loop) and pad slots [cnt+1..32] with self (alpha=0 later)
    if (t >= cnt && t < SLOTS) s_nbr[t] = i;
    __syncthreads();
    const int total = cnt + 1;            // valid slots: 0..cnt (incl. self)

    const size_t bbase = (size_t)b * NN * HD;

    // ---- Phase B1: issue ALL neighbor gathers first (latency hiding) ----
    float xlv[SLOTS];
    #pragma unroll
    for (int k = 0; k < SLOTS; ++k)
        xlv[k] = XL[bbase + (size_t)s_nbr[k] * HD + t];

    // ---- Phase B2: e_k = att . leaky_relu(xl_k + xr) via wave reduce ----
    #pragma unroll
    for (int k = 0; k < SLOTS; ++k) {
        float s = xlv[k] + xr;
        s = fmaxf(s, 0.f) + 0.2f * fminf(s, 0.f);   // leaky_relu, branchless
        float c = attv * s;
        #pragma unroll
        for (int off = 32; off; off >>= 1) c += __shfl_xor(c, off);
        if (lane == 0) s_a[h][k] = c;
    }
    __syncthreads();

    // ---- softmax over slots (one wave per head, slots fit in 64 lanes) ----
    float e = (lane < total) ? s_a[h][lane] : -3.0e38f;
    float m = e;
    #pragma unroll
    for (int off = 32; off; off >>= 1) m = fmaxf(m, __shfl_xor(m, off));
    float p = (lane < total) ? __expf(e - m) : 0.f;
    float sm = p;
    #pragma unroll
    for (int off = 32; off; off >>= 1) sm += __shfl_xor(sm, off);
    float alpha = p / sm;                 // 0 for padded slots
    if (lane < SLOTS) s_a[h][lane] = alpha;
    __syncthreads();

    // ---- aggregate from registers + bias ----
    float acc = 0.f;
    #pragma unroll
    for (int k = 0; k < SLOTS; ++k) acc = fmaf(s_a[h][k], xlv[k], acc);
    acc += biasv;

    // ---- LayerNorm over 256 features (two-pass, block reduce) ----
    float ssum = acc;
    #pragma unroll
    for (int off = 32; off; off >>= 1) ssum += __shfl_xor(ssum, off);
    if (lane == 0) s_red[h] = ssum;
    __syncthreads();
    float mu = (s_red[0] + s_red[1] + s_red[2] + s_red[3]) * (1.f / 256.f);
    __syncthreads();
    float d  = acc - mu;
    float dv = d * d;
    #pragma unroll
    for (int off = 32; off; off >>= 1) dv += __shfl_xor(dv, off);
    if (lane == 0) s_red[h] = dv;
    __syncthreads();
    float var  = (s_red[0] + s_red[1] + s_red[2] + s_red[3]) * (1.f / 256.f);
    float rstd = rsqrtf(var + 1e-5f);
    out[(size_t)node * HD + t] = d * rstd * gv + bv;
}

// ---------------------------------------------------------------------------
extern "C" void kernel_launch(void* const* d_in, const int* in_sizes, int n_in,
                              void* d_out, int out_size, void* d_ws, size_t ws_size,
                              hipStream_t stream)
{
    const float* x     = (const float*)d_in[0];
    const float* adj   = (const float*)d_in[1];
    const float* Wl    = (const float*)d_in[2];
    const float* bl    = (const float*)d_in[3];
    const float* Wr    = (const float*)d_in[4];
    const float* br    = (const float*)d_in[5];
    const float* att   = (const float*)d_in[6];
    const float* bias  = (const float*)d_in[7];
    const float* gamma = (const float*)d_in[8];
    const float* beta  = (const float*)d_in[9];
    float* out = (float*)d_out;

    float* XL = (float*)d_ws;                       // 16 MiB
    float* XR = XL + (size_t)BB * NN * HD;          // 16 MiB

    xlr_kernel<<<BB * NN / 32, 256, 0, stream>>>(x, Wl, bl, Wr, br, XL, XR);
    gat_kernel<<<BB * NN, 256, 0, stream>>>(adj, XL, XR, att, bias, gamma, beta, out);
}